// Round 8
// baseline (1277.852 us; speedup 1.0000x reference)
//
#include <hip/hip_runtime.h>
#include <hip/hip_cooperative_groups.h>
#include <cmath>
#include <cstdint>

namespace cg = cooperative_groups;

// GCNConv(C=256 -> 1, add_self_loops, symmetric norm) + Softplus
//
// Single cooperative mega-kernel: 6 phases separated by grid.sync().
// Atomic-free (R1-R3: gfx950 scatter global atomics run memory-side at
// ~19 G/s — unusable). Counting sort by 128-node dst bucket + LDS agg.
//
//  P0: h[n]=dot(x[n,:],W) (wave-per-row) + per-chunk bucket hist -> countsT
//  P1: btot[j] = sum_b countsT[j][b]
//  P2: bbase[j] = sum_{k<j} btot[k] ; baseT[j][b] = bbase[j]+prefix
//  P3: sorted[pos] = (dst&127)<<17 | src   (LDS rank atomics only)
//  P4: per-bucket LDS u32 hist -> dinv, g = dinv*h
//  P5: per-bucket LDS f32 acc of g[src] + self-loop -> softplus -> out

#define NBSHIFT 7
#define NLOCAL  (1 << NBSHIFT)      // 128 nodes per bucket
#define NBLK    1024                // grid size == chunk count
#define SRCBITS 17                  // N=100000 < 2^17

__global__ __launch_bounds__(256, 4) void k_mega(
        const float* __restrict__ x,
        const float* __restrict__ W,
        const int* __restrict__ src,
        const int* __restrict__ dst,
        const float* __restrict__ bias,
        float* __restrict__ out,
        float* __restrict__ h,
        float* __restrict__ dinv,
        float* __restrict__ g,
        unsigned* __restrict__ sorted,
        unsigned* __restrict__ countsT,   // [NB][NBLK]
        unsigned* __restrict__ baseT,     // [NB][NBLK]
        unsigned* __restrict__ btot,      // [NB]
        unsigned* __restrict__ bbase,     // [NB]
        int N, int E, int NB, int CH) {
    cg::grid_group grid = cg::this_grid();
    __shared__ unsigned shm[2048];        // 8 KB, aliased per phase

    const int t   = threadIdx.x;
    const int blk = blockIdx.x;

    // ---------------- P0: dot + per-chunk bucket histogram ----------------
    {
        int lane = t & 63;
        int nw   = (NBLK * 256) >> 6;
        const float4 wv = *reinterpret_cast<const float4*>(W + lane * 4);
        for (int row = (blk * 256 + t) >> 6; row < N; row += nw) {
            const float4 xv = *reinterpret_cast<const float4*>(x + (size_t)row * 256 + lane * 4);
            float s = xv.x * wv.x + xv.y * wv.y + xv.z * wv.z + xv.w * wv.w;
            #pragma unroll
            for (int o = 32; o >= 1; o >>= 1) s += __shfl_xor(s, o, 64);
            if (lane == 0) h[row] = s;
        }

        unsigned* cnt = shm;                       // [1024], NB used
        for (int j = t; j < 1024; j += 256) cnt[j] = 0;
        __syncthreads();
        int cs = blk * CH, ce = min(E, cs + CH);
        int e4 = cs + (((ce - cs) >> 2) << 2);
        for (int i = cs + t * 4; i < e4; i += 1024) {
            int4 v = *reinterpret_cast<const int4*>(dst + i);
            atomicAdd(&cnt[((unsigned)v.x) >> NBSHIFT], 1u);
            atomicAdd(&cnt[((unsigned)v.y) >> NBSHIFT], 1u);
            atomicAdd(&cnt[((unsigned)v.z) >> NBSHIFT], 1u);
            atomicAdd(&cnt[((unsigned)v.w) >> NBSHIFT], 1u);
        }
        for (int i = e4 + t; i < ce; i += 256)
            atomicAdd(&cnt[((unsigned)dst[i]) >> NBSHIFT], 1u);
        __syncthreads();
        for (int j = t; j < NB; j += 256)
            countsT[(size_t)j * NBLK + blk] = cnt[j];
    }
    __threadfence();
    grid.sync();

    // ---------------- P1: btot[j] = row reduce of countsT ----------------
    if (blk < NB) {
        unsigned* red = shm;
        uint4 c = *reinterpret_cast<const uint4*>(countsT + (size_t)blk * NBLK + t * 4);
        red[t] = c.x + c.y + c.z + c.w;
        __syncthreads();
        for (int s = 128; s > 0; s >>= 1) {
            if (t < s) red[t] += red[t + s];
            __syncthreads();
        }
        if (t == 0) btot[blk] = red[0];
    }
    __threadfence();
    grid.sync();

    // ---------------- P2: bbase[j] + row exclusive scan -> baseT ----------------
    if (blk < NB) {
        unsigned* red = shm;            // [256]
        unsigned* arr = shm + 256;      // [256]
        // bbase[j] = sum_{k<j} btot[k]
        unsigned v = 0;
        for (int k = t; k < blk; k += 256) v += btot[k];
        red[t] = v;
        __syncthreads();
        for (int s = 128; s > 0; s >>= 1) {
            if (t < s) red[t] += red[t + s];
            __syncthreads();
        }
        if (t == 0) { shm[512] = red[0]; bbase[blk] = red[0]; }
        // row exclusive scan over NBLK block-counts
        uint4 c = *reinterpret_cast<const uint4*>(countsT + (size_t)blk * NBLK + t * 4);
        unsigned own = c.x + c.y + c.z + c.w;
        arr[t] = own;
        __syncthreads();
        for (int off = 1; off < 256; off <<= 1) {
            unsigned add = (t >= off) ? arr[t - off] : 0u;
            __syncthreads();
            arr[t] += add;
            __syncthreads();
        }
        unsigned base = shm[512] + (arr[t] - own);
        uint4 o;
        o.x = base;
        o.y = base + c.x;
        o.z = base + c.x + c.y;
        o.w = base + c.x + c.y + c.z;
        *reinterpret_cast<uint4*>(baseT + (size_t)blk * NBLK + t * 4) = o;
    }
    __threadfence();
    grid.sync();

    // ---------------- P3: partition chunk blk -> sorted ----------------
    {
        unsigned* base = shm;           // [1024]
        unsigned* rank = shm + 1024;    // [1024]
        for (int j = t; j < 1024; j += 256) rank[j] = 0;
        for (int j = t; j < NB; j += 256) base[j] = baseT[(size_t)j * NBLK + blk];
        __syncthreads();
        int cs = blk * CH, ce = min(E, cs + CH);
        int e4 = cs + (((ce - cs) >> 2) << 2);
        for (int i = cs + t * 4; i < e4; i += 1024) {
            int4 dv = *reinterpret_cast<const int4*>(dst + i);
            int4 sv = *reinterpret_cast<const int4*>(src + i);
            unsigned d, j, r;
            d = (unsigned)dv.x; j = d >> NBSHIFT; r = atomicAdd(&rank[j], 1u);
            sorted[base[j] + r] = ((d & (NLOCAL - 1u)) << SRCBITS) | (unsigned)sv.x;
            d = (unsigned)dv.y; j = d >> NBSHIFT; r = atomicAdd(&rank[j], 1u);
            sorted[base[j] + r] = ((d & (NLOCAL - 1u)) << SRCBITS) | (unsigned)sv.y;
            d = (unsigned)dv.z; j = d >> NBSHIFT; r = atomicAdd(&rank[j], 1u);
            sorted[base[j] + r] = ((d & (NLOCAL - 1u)) << SRCBITS) | (unsigned)sv.z;
            d = (unsigned)dv.w; j = d >> NBSHIFT; r = atomicAdd(&rank[j], 1u);
            sorted[base[j] + r] = ((d & (NLOCAL - 1u)) << SRCBITS) | (unsigned)sv.w;
        }
        for (int i = e4 + t; i < ce; i += 256) {
            unsigned d = (unsigned)dst[i];
            unsigned j = d >> NBSHIFT;
            unsigned r = atomicAdd(&rank[j], 1u);
            sorted[base[j] + r] = ((d & (NLOCAL - 1u)) << SRCBITS) | (unsigned)src[i];
        }
    }
    __threadfence();
    grid.sync();

    // ---------------- P4: per-bucket degree -> dinv, g ----------------
    if (blk < NB) {
        unsigned* acc = shm;            // [NLOCAL]
        if (t < NLOCAL) acc[t] = 0;
        __syncthreads();
        unsigned s0 = bbase[blk], e0 = s0 + btot[blk];
        for (unsigned i = s0 + t; i < e0; i += 256)
            atomicAdd(&acc[sorted[i] >> SRCBITS], 1u);
        __syncthreads();
        if (t < NLOCAL) {
            int n = (blk << NBSHIFT) + t;
            if (n < N) {
                float di = rsqrtf((float)(acc[t] + 1u));   // +1 self-loop
                dinv[n] = di;
                g[n]    = di * h[n];
            }
        }
    }
    __threadfence();
    grid.sync();

    // ---------------- P5: per-bucket aggregate + softplus -> out ----------------
    if (blk < NB) {
        float* acc = (float*)shm;       // [NLOCAL]
        if (t < NLOCAL) acc[t] = 0.0f;
        __syncthreads();
        unsigned s0 = bbase[blk], e0 = s0 + btot[blk];
        for (unsigned i = s0 + t; i < e0; i += 256) {
            unsigned p = sorted[i];
            atomicAdd(&acc[p >> SRCBITS], g[p & ((1u << SRCBITS) - 1u)]);
        }
        __syncthreads();
        if (t < NLOCAL) {
            int n = (blk << NBSHIFT) + t;
            if (n < N) {
                float v = dinv[n] * (acc[t] + g[n]) + bias[0];
                out[n] = fmaxf(v, 0.0f) + log1pf(expf(-fabsf(v)));  // stable softplus
            }
        }
    }
}

extern "C" void kernel_launch(void* const* d_in, const int* in_sizes, int n_in,
                              void* d_out, int out_size, void* d_ws, size_t ws_size,
                              hipStream_t stream) {
    const float* x  = (const float*)d_in[0];
    const int*   ei = (const int*)d_in[1];
    const float* W  = (const float*)d_in[2];
    const float* b  = (const float*)d_in[3];
    float* out = (float*)d_out;

    int N = in_sizes[0] / 256;
    int E = in_sizes[1] / 2;
    const int* src = ei;
    const int* dst = ei + E;

    int NB = (N + NLOCAL - 1) >> NBSHIFT;                 // 782
    int CH = (((E + NBLK - 1) / NBLK) + 3) & ~3;          // multiple of 4

    float*    h       = (float*)d_ws;                     // N
    float*    dinv    = h + N;                            // N
    float*    g       = dinv + N;                         // N
    unsigned* sorted  = (unsigned*)(g + N);               // E
    unsigned* countsT = sorted + E;                       // NB*NBLK
    unsigned* baseT   = countsT + (size_t)NB * NBLK;      // NB*NBLK
    unsigned* btot    = baseT + (size_t)NB * NBLK;        // NB
    unsigned* bbase   = btot + NB;                        // NB

    void* args[] = { &x, &W, &src, &dst, &b, &out,
                     &h, &dinv, &g, &sorted, &countsT, &baseT, &btot, &bbase,
                     &N, &E, &NB, &CH };
    hipLaunchCooperativeKernel((void*)k_mega, dim3(NBLK), dim3(256),
                               args, 0, stream);
}

// Round 9
// 257.801 us; speedup vs baseline: 4.9567x; 4.9567x over previous
//
#include <hip/hip_runtime.h>
#include <cmath>
#include <cstdint>

// GCNConv(C=256 -> 1, add_self_loops, symmetric norm) + Softplus
//
// Atomic-free pipeline (R1-R3: gfx950 scatter global atomics run memory-side,
// ~19 G/s, 32 B HBM write-through each). R8: grid.sync() costs ~220 us/sync
// on gfx950 — cooperative mega-kernel abandoned; separate dispatches win.
//
//  k_front: h[n]=dot(x[n,:],W) (wave-per-row) + chunk bucket hist -> countsT
//           + clears pub[] (d_ws is 0xAA-poisoned every call)
//  k_scan : one kernel: row-reduce -> publish total (memory-side atomic,
//           coherent) -> parallel lookback sum -> bbase, btot, baseT
//  k_part : sorted[pos] = (dst&127)<<17 | src    (LDS rank atomics only)
//  k_deg  : per-bucket LDS u32 hist -> dinv, g = dinv*h      (512 thr)
//  k_agg  : per-bucket LDS f32 acc of g[src] + self-loop -> softplus (512 thr)

#define NBSHIFT 7
#define NLOCAL  (1 << NBSHIFT)      // 128 nodes per bucket
#define NBLK    1024                // chunk count for count/partition
#define SRCBITS 17                  // N=100000 < 2^17
#define PUBFLAG (1ULL << 63)

__global__ __launch_bounds__(256) void k_front(const float* __restrict__ x,
                                               const float* __restrict__ W,
                                               const int* __restrict__ dst,
                                               float* __restrict__ h,
                                               unsigned* __restrict__ countsT, // [NB][NBLK]
                                               unsigned long long* __restrict__ pub,
                                               int N, int E, int NB, int CH) {
    const int t = threadIdx.x, blk = blockIdx.x;

    // clear publish flags for k_scan (ws is poisoned to 0xAA every call)
    if (blk == 0)
        for (int j = t; j < NB; j += 256) pub[j] = 0ULL;

    // ---- phase A: wave-per-row dot(x[row,:], W) ----
    {
        int lane = t & 63;
        int nw   = (NBLK * 256) >> 6;
        const float4 wv = *reinterpret_cast<const float4*>(W + lane * 4);
        for (int row = (blk * 256 + t) >> 6; row < N; row += nw) {
            const float4 xv = *reinterpret_cast<const float4*>(x + (size_t)row * 256 + lane * 4);
            float s = xv.x * wv.x + xv.y * wv.y + xv.z * wv.z + xv.w * wv.w;
            #pragma unroll
            for (int o = 32; o >= 1; o >>= 1) s += __shfl_xor(s, o, 64);
            if (lane == 0) h[row] = s;
        }
    }

    // ---- phase B: per-chunk bucket histogram (LDS atomics only) ----
    __shared__ unsigned cnt[1024];
    for (int j = t; j < 1024; j += 256) cnt[j] = 0;
    __syncthreads();
    int cs = blk * CH, ce = min(E, cs + CH);
    int e8 = cs + (((ce - cs) >> 3) << 3);
    for (int i = cs + t * 8; i < e8; i += 2048) {
        int4 a = *reinterpret_cast<const int4*>(dst + i);
        int4 c = *reinterpret_cast<const int4*>(dst + i + 4);
        atomicAdd(&cnt[((unsigned)a.x) >> NBSHIFT], 1u);
        atomicAdd(&cnt[((unsigned)a.y) >> NBSHIFT], 1u);
        atomicAdd(&cnt[((unsigned)a.z) >> NBSHIFT], 1u);
        atomicAdd(&cnt[((unsigned)a.w) >> NBSHIFT], 1u);
        atomicAdd(&cnt[((unsigned)c.x) >> NBSHIFT], 1u);
        atomicAdd(&cnt[((unsigned)c.y) >> NBSHIFT], 1u);
        atomicAdd(&cnt[((unsigned)c.z) >> NBSHIFT], 1u);
        atomicAdd(&cnt[((unsigned)c.w) >> NBSHIFT], 1u);
    }
    for (int i = e8 + t; i < ce; i += 256)
        atomicAdd(&cnt[((unsigned)dst[i]) >> NBSHIFT], 1u);
    __syncthreads();
    for (int j = t; j < NB; j += 256)
        countsT[(size_t)j * NBLK + blk] = cnt[j];
}

__global__ __launch_bounds__(256) void k_scan(const unsigned* __restrict__ countsT,
                                              unsigned long long* __restrict__ pub,
                                              unsigned* __restrict__ btot,
                                              unsigned* __restrict__ bbase,
                                              unsigned* __restrict__ baseT,
                                              int NB) {
    __shared__ unsigned red[256];
    __shared__ unsigned arr[256];
    __shared__ unsigned sBase;
    int j = blockIdx.x, t = threadIdx.x;

    // row reduce of own bucket's per-chunk counts
    uint4 c = *reinterpret_cast<const uint4*>(countsT + (size_t)j * NBLK + t * 4);
    unsigned own = c.x + c.y + c.z + c.w;
    red[t] = own;
    __syncthreads();
    for (int s = 128; s > 0; s >>= 1) {
        if (t < s) red[t] += red[t + s];
        __syncthreads();
    }
    unsigned total = red[0];
    if (t == 0) {
        btot[j] = total;
        atomicExch(&pub[j], PUBFLAG | (unsigned long long)total);  // publish (memory-side)
    }

    // lookback: sum all predecessor totals (publish precedes wait => no deadlock;
    // probes are returning atomics => always fresh, never stale L2)
    unsigned v = 0;
    for (int k = t; k < j; k += 256) {
        unsigned long long p;
        while (!((p = atomicAdd(&pub[k], 0ULL)) & PUBFLAG))
            __builtin_amdgcn_s_sleep(2);
        v += (unsigned)p;
    }
    __syncthreads();
    red[t] = v;
    __syncthreads();
    for (int s = 128; s > 0; s >>= 1) {
        if (t < s) red[t] += red[t + s];
        __syncthreads();
    }
    if (t == 0) { sBase = red[0]; bbase[j] = red[0]; }

    // row exclusive scan over NBLK chunk-counts -> per-chunk write bases
    arr[t] = own;
    __syncthreads();
    for (int off = 1; off < 256; off <<= 1) {
        unsigned add = (t >= off) ? arr[t - off] : 0u;
        __syncthreads();
        arr[t] += add;
        __syncthreads();
    }
    unsigned base = sBase + (arr[t] - own);
    uint4 o;
    o.x = base;
    o.y = base + c.x;
    o.z = base + c.x + c.y;
    o.w = base + c.x + c.y + c.z;
    *reinterpret_cast<uint4*>(baseT + (size_t)j * NBLK + t * 4) = o;
}

__global__ __launch_bounds__(256) void k_part(const int* __restrict__ src,
                                              const int* __restrict__ dst,
                                              const unsigned* __restrict__ baseT,
                                              unsigned* __restrict__ sorted,
                                              int E, int NB, int CH) {
    __shared__ unsigned base[1024];
    __shared__ unsigned rank[1024];
    const int t = threadIdx.x, blk = blockIdx.x;
    for (int j = t; j < 1024; j += 256) rank[j] = 0;
    for (int j = t; j < NB; j += 256) base[j] = baseT[(size_t)j * NBLK + blk];
    __syncthreads();
    int cs = blk * CH, ce = min(E, cs + CH);
    int e4 = cs + (((ce - cs) >> 2) << 2);
    for (int i = cs + t * 4; i < e4; i += 1024) {
        int4 dv = *reinterpret_cast<const int4*>(dst + i);
        int4 sv = *reinterpret_cast<const int4*>(src + i);
        unsigned d, j, r;
        d = (unsigned)dv.x; j = d >> NBSHIFT; r = atomicAdd(&rank[j], 1u);
        sorted[base[j] + r] = ((d & (NLOCAL - 1u)) << SRCBITS) | (unsigned)sv.x;
        d = (unsigned)dv.y; j = d >> NBSHIFT; r = atomicAdd(&rank[j], 1u);
        sorted[base[j] + r] = ((d & (NLOCAL - 1u)) << SRCBITS) | (unsigned)sv.y;
        d = (unsigned)dv.z; j = d >> NBSHIFT; r = atomicAdd(&rank[j], 1u);
        sorted[base[j] + r] = ((d & (NLOCAL - 1u)) << SRCBITS) | (unsigned)sv.z;
        d = (unsigned)dv.w; j = d >> NBSHIFT; r = atomicAdd(&rank[j], 1u);
        sorted[base[j] + r] = ((d & (NLOCAL - 1u)) << SRCBITS) | (unsigned)sv.w;
    }
    for (int i = e4 + t; i < ce; i += 256) {
        unsigned d = (unsigned)dst[i];
        unsigned j = d >> NBSHIFT;
        unsigned r = atomicAdd(&rank[j], 1u);
        sorted[base[j] + r] = ((d & (NLOCAL - 1u)) << SRCBITS) | (unsigned)src[i];
    }
}

__global__ __launch_bounds__(512) void k_deg(const unsigned* __restrict__ sorted,
                                             const unsigned* __restrict__ bbase,
                                             const unsigned* __restrict__ btot,
                                             const float* __restrict__ h,
                                             float* __restrict__ dinv,
                                             float* __restrict__ g,
                                             int N) {
    __shared__ unsigned acc[NLOCAL];
    int j = blockIdx.x, t = threadIdx.x;
    if (t < NLOCAL) acc[t] = 0;
    __syncthreads();
    unsigned s0 = bbase[j], e0 = s0 + btot[j];
    for (unsigned i = s0 + t; i < e0; i += 512)
        atomicAdd(&acc[sorted[i] >> SRCBITS], 1u);
    __syncthreads();
    if (t < NLOCAL) {
        int n = (j << NBSHIFT) + t;
        if (n < N) {
            float di = rsqrtf((float)(acc[t] + 1u));   // +1 self-loop
            dinv[n] = di;
            g[n]    = di * h[n];
        }
    }
}

__global__ __launch_bounds__(512) void k_agg(const unsigned* __restrict__ sorted,
                                             const unsigned* __restrict__ bbase,
                                             const unsigned* __restrict__ btot,
                                             const float* __restrict__ g,
                                             const float* __restrict__ dinv,
                                             const float* __restrict__ b,
                                             float* __restrict__ out,
                                             int N) {
    __shared__ float acc[NLOCAL];
    int j = blockIdx.x, t = threadIdx.x;
    if (t < NLOCAL) acc[t] = 0.0f;
    __syncthreads();
    unsigned s0 = bbase[j], e0 = s0 + btot[j];
    for (unsigned i = s0 + t; i < e0; i += 512) {
        unsigned p = sorted[i];
        atomicAdd(&acc[p >> SRCBITS], g[p & ((1u << SRCBITS) - 1u)]);
    }
    __syncthreads();
    if (t < NLOCAL) {
        int n = (j << NBSHIFT) + t;
        if (n < N) {
            float v = dinv[n] * (acc[t] + g[n]) + b[0];
            out[n] = fmaxf(v, 0.0f) + log1pf(expf(-fabsf(v)));  // stable softplus
        }
    }
}

extern "C" void kernel_launch(void* const* d_in, const int* in_sizes, int n_in,
                              void* d_out, int out_size, void* d_ws, size_t ws_size,
                              hipStream_t stream) {
    const float* x  = (const float*)d_in[0];
    const int*   ei = (const int*)d_in[1];
    const float* W  = (const float*)d_in[2];
    const float* b  = (const float*)d_in[3];
    float* out = (float*)d_out;

    int N = in_sizes[0] / 256;
    int E = in_sizes[1] / 2;
    const int* src = ei;
    const int* dst = ei + E;

    int NB = (N + NLOCAL - 1) >> NBSHIFT;                 // 782
    int CH = (((E + NBLK - 1) / NBLK) + 7) & ~7;          // multiple of 8

    float*    h       = (float*)d_ws;                     // N
    float*    dinv    = h + N;                            // N
    float*    g       = dinv + N;                         // N
    unsigned* sorted  = (unsigned*)(g + N);               // E
    unsigned* countsT = sorted + E;                       // NB*NBLK
    unsigned* baseT   = countsT + (size_t)NB * NBLK;      // NB*NBLK
    unsigned* btot    = baseT + (size_t)NB * NBLK;        // NB
    unsigned* bbase   = btot + NB;                        // NB
    // 8-byte aligned publish array for k_scan
    uintptr_t pa = (uintptr_t)(bbase + NB);
    unsigned long long* pub = (unsigned long long*)((pa + 7) & ~(uintptr_t)7);

    k_front<<<NBLK, 256, 0, stream>>>(x, W, dst, h, countsT, pub, N, E, NB, CH);
    k_scan <<<NB, 256, 0, stream>>>(countsT, pub, btot, bbase, baseT, NB);
    k_part <<<NBLK, 256, 0, stream>>>(src, dst, baseT, sorted, E, NB, CH);
    k_deg  <<<NB, 512, 0, stream>>>(sorted, bbase, btot, h, dinv, g, N);
    k_agg  <<<NB, 512, 0, stream>>>(sorted, bbase, btot, g, dinv, b, out, N);
}